// Round 1
// baseline (2404.665 us; speedup 1.0000x reference)
//
#include <hip/hip_runtime.h>
#include <hip/hip_bf16.h>
#include <math.h>

typedef __bf16 bh;
typedef __bf16 bh8 __attribute__((ext_vector_type(8)));
typedef __bf16 bh4 __attribute__((ext_vector_type(4)));
typedef float f32x4 __attribute__((ext_vector_type(4)));

typedef const unsigned int __attribute__((address_space(1))) guint;
typedef unsigned int __attribute__((address_space(3))) luint;

#define DEV __device__ __forceinline__

DEV void gl16(const void* g, void* s) {
  __builtin_amdgcn_global_load_lds((guint*)g, (luint*)s, 16, 0, 0);
}

// ---------------------------------------------------------------------------
// 128x128 GEMM core: C = A[M,K] * BT[N,K]^T, bf16 inputs, f32 acc.
// 4 waves; wave (wr,wc) owns 64x64; 16x16x32 MFMA; BK=32; global_load_lds w=16.
// LDS chunk swizzle: logical 16B chunk lc of row r lives at phys=(lc+(r>>1))&3.
// ---------------------------------------------------------------------------
DEV void gemm_core(const bh* __restrict__ A, const bh* __restrict__ BT, int K,
                   int arow0, int brow0, char* sm, f32x4 acc[4][4]) {
  const int t = threadIdx.x;
  const int w = t >> 6, l = t & 63;
  const int wr = w >> 1, wc = w & 1;
  const int srow = t >> 2, sphys = t & 3;
  const int slc = (sphys - (srow >> 1)) & 3;
  const bh* ga0 = A + (size_t)(arow0 + srow) * K + slc * 8;
  const bh* ga1 = A + (size_t)(arow0 + srow + 64) * K + slc * 8;
  const bh* gb0 = BT + (size_t)(brow0 + srow) * K + slc * 8;
  const bh* gb1 = BT + (size_t)(brow0 + srow + 64) * K + slc * 8;
  char* As = sm;
  char* Bs = sm + 8192;
  char* lA0 = As + w * 1024;          // wave-uniform LDS bases
  char* lA1 = As + 4096 + w * 1024;
  char* lB0 = Bs + w * 1024;
  char* lB1 = Bs + 4096 + w * 1024;
  const int rA = wr * 64 + (l & 15);
  const int rB = wc * 64 + (l & 15);
  const int g = l >> 4;
  for (int k0 = 0; k0 < K; k0 += 32) {
    gl16(ga0 + k0, lA0);
    gl16(ga1 + k0, lA1);
    gl16(gb0 + k0, lB0);
    gl16(gb1 + k0, lB1);
    __syncthreads();
    bh8 af[4], bfv[4];
#pragma unroll
    for (int m = 0; m < 4; m++) {
      int row = rA + m * 16;
      int ph = (g + (row >> 1)) & 3;
      af[m] = *(const bh8*)(As + row * 64 + ph * 16);
    }
#pragma unroll
    for (int n = 0; n < 4; n++) {
      int row = rB + n * 16;
      int ph = (g + (row >> 1)) & 3;
      bfv[n] = *(const bh8*)(Bs + row * 64 + ph * 16);
    }
#pragma unroll
    for (int m = 0; m < 4; m++)
#pragma unroll
      for (int n = 0; n < 4; n++)
        acc[m][n] = __builtin_amdgcn_mfma_f32_16x16x32_bf16(af[m], bfv[n], acc[m][n], 0, 0, 0);
    __syncthreads();
  }
}

// QKV projection: z=0 -> q, z=1 -> k, z=2 -> v written transposed per head
// wqkvT layout: [3][L][1024][1024]; WT passed pre-offset by layer l.
__global__ __launch_bounds__(256) void k_gemm_qkv(
    const bh* __restrict__ A, const bh* __restrict__ WT,
    const float* __restrict__ bq, const float* __restrict__ bk, const float* __restrict__ bv,
    bh* __restrict__ qo, bh* __restrict__ ko, bh* __restrict__ vT) {
  __shared__ __align__(16) char sm[16384];
  const int z = blockIdx.z;
  const bh* BT = WT + (size_t)z * 6291456;  // 6*1024*1024
  f32x4 acc[4][4] = {};
  gemm_core(A, BT, 1024, blockIdx.y * 128, blockIdx.x * 128, sm, acc);
  const float* bias = (z == 0) ? bq : (z == 1) ? bk : bv;
  bh* outp = (z == 0) ? qo : ko;
  const int t = threadIdx.x, w = t >> 6, l = t & 63;
  const int r0 = blockIdx.y * 128 + (w >> 1) * 64 + (l >> 4) * 4;
  const int c0 = blockIdx.x * 128 + (w & 1) * 64 + (l & 15);
#pragma unroll
  for (int n = 0; n < 4; n++) {
    int col = c0 + n * 16;
    float bb = bias[col];
#pragma unroll
    for (int m = 0; m < 4; m++) {
#pragma unroll
      for (int j = 0; j < 4; j++) {
        int row = r0 + m * 16 + j;
        float v = acc[m][n][j] + bb;
        if (z < 2) {
          outp[(size_t)row * 1024 + col] = (bh)v;
        } else {
          int b = row >> 10, s = row & 1023, hh = col >> 6, d = col & 63;
          vT[(((size_t)(b * 16 + hh) * 64 + d) << 10) + s] = (bh)v;
        }
      }
    }
  }
}

// Generic epilogue GEMM. MODE: 2 = bias+GELU -> bf16; 3 = bias+res -> f32; 4 = bias -> f32
template <int MODE>
__global__ __launch_bounds__(256) void k_gemm_epi(
    const bh* __restrict__ A, const bh* __restrict__ BT, const float* __restrict__ bias,
    const float* __restrict__ res, void* __restrict__ out, int N, int K) {
  __shared__ __align__(16) char sm[16384];
  f32x4 acc[4][4] = {};
  gemm_core(A, BT, K, blockIdx.y * 128, blockIdx.x * 128, sm, acc);
  const int t = threadIdx.x, w = t >> 6, l = t & 63;
  const int r0 = blockIdx.y * 128 + (w >> 1) * 64 + (l >> 4) * 4;
  const int c0 = blockIdx.x * 128 + (w & 1) * 64 + (l & 15);
#pragma unroll
  for (int n = 0; n < 4; n++) {
    int col = c0 + n * 16;
    float bb = bias[col];
#pragma unroll
    for (int m = 0; m < 4; m++) {
#pragma unroll
      for (int j = 0; j < 4; j++) {
        int row = r0 + m * 16 + j;
        float v = acc[m][n][j] + bb;
        size_t idx = (size_t)row * N + col;
        if (MODE == 2) {
          v = 0.5f * v * (1.0f + erff(v * 0.70710678118654752f));
          ((bh*)out)[idx] = (bh)v;
        } else if (MODE == 3) {
          ((float*)out)[idx] = v + res[idx];
        } else {
          ((float*)out)[idx] = v;
        }
      }
    }
  }
}

// ---------------------------------------------------------------------------
// Causal flash attention. Block = (q-tile of 64) x (b,h). 4 waves x 16 q-rows.
// qin,kin: [B,S,D] bf16 (head at col h*64). vin: [B,H,64,S] bf16 (pre-transposed).
// K/V tiles staged swizzled (phys chunk = (lc+row)&7); P via per-wave LDS.
// ---------------------------------------------------------------------------
__global__ __launch_bounds__(256) void k_attn(const bh* __restrict__ qin, const bh* __restrict__ kin,
                                              const bh* __restrict__ vin, bh* __restrict__ cout) {
  __shared__ __align__(16) char sm[24576];
  char* Ks = sm;           // [64 keys][64 d] bf16, swizzled
  char* Vs = sm + 8192;    // [64 d][64 keys] bf16, swizzled
  char* Ps = sm + 16384;   // per-wave [16 q][64 keys] bf16, swizzled
  const int t = threadIdx.x, w = t >> 6, l = t & 63;
  const int bx = blockIdx.x, bhid = blockIdx.y;
  const int b = bhid >> 4, hh = bhid & 15;
  const int q0 = bx * 64;
  const int g = l >> 4, c = l & 15;
  const int qrow = q0 + w * 16 + c;
  const bh* qp = qin + ((size_t)(b * 1024 + qrow)) * 1024 + hh * 64 + g * 8;
  bh8 aq0 = *(const bh8*)qp;
  bh8 aq1 = *(const bh8*)(qp + 32);
  f32x4 cacc[4] = {};
  float m_[4] = {-1e30f, -1e30f, -1e30f, -1e30f};
  float l_[4] = {0.f, 0.f, 0.f, 0.f};
  const int srow = t >> 3, sphys = t & 7;
  const int slc = (sphys - srow) & 7;
  const bh* kg = kin + ((size_t)(b * 1024 + srow)) * 1024 + hh * 64 + slc * 8;
  const bh* vg = vin + ((size_t)bhid * 64 + srow) * 1024 + slc * 8;
  char* Pw = Ps + w * 2048;
  for (int j = 0; j <= bx; j++) {
    const bh* kp = kg + (size_t)j * 65536;
    const bh* vp = vg + j * 64;
    gl16(kp, Ks + w * 1024);
    gl16(kp + 32768, Ks + 4096 + w * 1024);
    gl16(vp, Vs + w * 1024);
    gl16(vp + 32768, Vs + 4096 + w * 1024);
    __syncthreads();
    f32x4 s[4];
#pragma unroll
    for (int n = 0; n < 4; n++) {
      int key = n * 16 + c;
      int p0 = (g + key) & 7;
      int p1 = (4 + g + key) & 7;
      bh8 kf0 = *(const bh8*)(Ks + key * 128 + p0 * 16);
      bh8 kf1 = *(const bh8*)(Ks + key * 128 + p1 * 16);
      f32x4 z = {};
      z = __builtin_amdgcn_mfma_f32_16x16x32_bf16(aq0, kf0, z, 0, 0, 0);
      z = __builtin_amdgcn_mfma_f32_16x16x32_bf16(aq1, kf1, z, 0, 0, 0);
      s[n] = z;
    }
#pragma unroll
    for (int n = 0; n < 4; n++)
#pragma unroll
      for (int r = 0; r < 4; r++) s[n][r] *= 0.125f;
    if (j == bx) {
#pragma unroll
      for (int n = 0; n < 4; n++) {
        int key = j * 64 + n * 16 + c;
#pragma unroll
        for (int r = 0; r < 4; r++) {
          int qr = q0 + w * 16 + g * 4 + r;
          if (key > qr) s[n][r] = -1e30f;
        }
      }
    }
#pragma unroll
    for (int r = 0; r < 4; r++) {
      float mx = fmaxf(fmaxf(s[0][r], s[1][r]), fmaxf(s[2][r], s[3][r]));
      mx = fmaxf(mx, __shfl_xor(mx, 1));
      mx = fmaxf(mx, __shfl_xor(mx, 2));
      mx = fmaxf(mx, __shfl_xor(mx, 4));
      mx = fmaxf(mx, __shfl_xor(mx, 8));
      float mn = fmaxf(m_[r], mx);
      float a = __expf(m_[r] - mn);
      m_[r] = mn;
      float sum = 0.f;
#pragma unroll
      for (int n = 0; n < 4; n++) {
        float p = __expf(s[n][r] - mn);
        s[n][r] = p;
        sum += p;
      }
      sum += __shfl_xor(sum, 1);
      sum += __shfl_xor(sum, 2);
      sum += __shfl_xor(sum, 4);
      sum += __shfl_xor(sum, 8);
      l_[r] = l_[r] * a + sum;
#pragma unroll
      for (int n = 0; n < 4; n++) cacc[n][r] *= a;
    }
#pragma unroll
    for (int n = 0; n < 4; n++) {
#pragma unroll
      for (int r = 0; r < 4; r++) {
        int row = g * 4 + r;
        int key = n * 16 + c;
        int ph = ((key >> 3) + row) & 7;
        *(bh*)(Pw + row * 128 + ph * 16 + (key & 7) * 2) = (bh)s[n][r];
      }
    }
    bh8 ap0, ap1;
    {
      int row = c;
      int p0 = (g + row) & 7;
      int p1 = (4 + g + row) & 7;
      ap0 = *(const bh8*)(Pw + row * 128 + p0 * 16);
      ap1 = *(const bh8*)(Pw + row * 128 + p1 * 16);
    }
#pragma unroll
    for (int n = 0; n < 4; n++) {
      int d = n * 16 + c;
      int p0 = (g + d) & 7;
      int p1 = (4 + g + d) & 7;
      bh8 v0 = *(const bh8*)(Vs + d * 128 + p0 * 16);
      bh8 v1 = *(const bh8*)(Vs + d * 128 + p1 * 16);
      cacc[n] = __builtin_amdgcn_mfma_f32_16x16x32_bf16(ap0, v0, cacc[n], 0, 0, 0);
      cacc[n] = __builtin_amdgcn_mfma_f32_16x16x32_bf16(ap1, v1, cacc[n], 0, 0, 0);
    }
    __syncthreads();
  }
#pragma unroll
  for (int r = 0; r < 4; r++) {
    float inv = 1.f / l_[r];
    int qr = q0 + w * 16 + g * 4 + r;
#pragma unroll
    for (int n = 0; n < 4; n++) {
      int d = hh * 64 + n * 16 + c;
      cout[((size_t)(b * 1024 + qr)) * 1024 + d] = (bh)(cacc[n][r] * inv);
    }
  }
}

// LayerNorm over rows of 1024: h = (t-mean)*rstd*g + b ; also bf16 copy.
__global__ __launch_bounds__(256) void k_ln(const float* __restrict__ tin, const float* __restrict__ gw,
                                            const float* __restrict__ bw, float* __restrict__ h,
                                            bh* __restrict__ hb) {
  const int row = blockIdx.x, tid = threadIdx.x;
  const float4 v = ((const float4*)(tin + (size_t)row * 1024))[tid];
  float s = v.x + v.y + v.z + v.w;
  float ss = v.x * v.x + v.y * v.y + v.z * v.z + v.w * v.w;
  s += __shfl_xor(s, 32); ss += __shfl_xor(ss, 32);
  s += __shfl_xor(s, 16); ss += __shfl_xor(ss, 16);
  s += __shfl_xor(s, 8);  ss += __shfl_xor(ss, 8);
  s += __shfl_xor(s, 4);  ss += __shfl_xor(ss, 4);
  s += __shfl_xor(s, 2);  ss += __shfl_xor(ss, 2);
  s += __shfl_xor(s, 1);  ss += __shfl_xor(ss, 1);
  __shared__ float as_[4], ass[4];
  if ((tid & 63) == 0) { as_[tid >> 6] = s; ass[tid >> 6] = ss; }
  __syncthreads();
  s = as_[0] + as_[1] + as_[2] + as_[3];
  ss = ass[0] + ass[1] + ass[2] + ass[3];
  const float mean = s * (1.f / 1024.f);
  const float var = ss * (1.f / 1024.f) - mean * mean;
  const float rstd = rsqrtf(var + 1e-5f);
  const float4 gv = ((const float4*)gw)[tid];
  const float4 bv = ((const float4*)bw)[tid];
  float4 o;
  o.x = (v.x - mean) * rstd * gv.x + bv.x;
  o.y = (v.y - mean) * rstd * gv.y + bv.y;
  o.z = (v.z - mean) * rstd * gv.z + bv.z;
  o.w = (v.w - mean) * rstd * gv.w + bv.w;
  ((float4*)(h + (size_t)row * 1024))[tid] = o;
  bh4 p = {(bh)o.x, (bh)o.y, (bh)o.z, (bh)o.w};
  *(bh4*)(hb + (size_t)row * 1024 + tid * 4) = p;
}

// Embedding * sqrt(D) + sinusoidal positional encoding.
__global__ __launch_bounds__(256) void k_embed(const int* __restrict__ x, const float* __restrict__ emb,
                                               float* __restrict__ h, bh* __restrict__ hb) {
  const int row = blockIdx.x, tid = threadIdx.x;
  const int s = row & 1023;
  const int tok = x[row];
  const float4 e = ((const float4*)(emb + (size_t)tok * 1024))[tid];
  const int d0 = tid * 4;
  float pe[4];
#pragma unroll
  for (int u = 0; u < 4; u++) {
    int d = d0 + u;
    int i2 = d & ~1;  // 2*i
    float fr = expf((float)i2 * (-9.210340371976184f / 1024.f));
    float ang = (float)s * fr;
    pe[u] = (d & 1) ? cosf(ang) : sinf(ang);
  }
  float4 o;
  o.x = e.x * 32.f + pe[0];
  o.y = e.y * 32.f + pe[1];
  o.z = e.z * 32.f + pe[2];
  o.w = e.w * 32.f + pe[3];
  ((float4*)(h + (size_t)row * 1024))[tid] = o;
  bh4 p = {(bh)o.x, (bh)o.y, (bh)o.z, (bh)o.w};
  *(bh4*)(hb + (size_t)row * 1024 + tid * 4) = p;
}

// f32 [R,C] -> bf16 [C,R] (per blockIdx.z matrix of R*C elements)
__global__ __launch_bounds__(256) void k_transpose(const float* __restrict__ in, bh* __restrict__ out,
                                                   int R, int C) {
  __shared__ float tile[64][65];
  const size_t moff = (size_t)blockIdx.z * R * C;
  const float* I = in + moff;
  bh* O = out + moff;
  const int r0 = blockIdx.y * 64, c0 = blockIdx.x * 64;
  const int tid = threadIdx.x;
  const int lr = tid >> 4, lc = (tid & 15) * 4;
#pragma unroll
  for (int i = 0; i < 4; i++) {
    const float4 v = *(const float4*)(I + (size_t)(r0 + lr + i * 16) * C + c0 + lc);
    tile[lr + i * 16][lc] = v.x;
    tile[lr + i * 16][lc + 1] = v.y;
    tile[lr + i * 16][lc + 2] = v.z;
    tile[lr + i * 16][lc + 3] = v.w;
  }
  __syncthreads();
  const int oc = tid >> 2, rr0 = (tid & 3) * 8;
#pragma unroll
  for (int hf = 0; hf < 2; hf++) {
    const int rr = rr0 + hf * 32;
    bh8 p;
#pragma unroll
    for (int jj = 0; jj < 8; jj++) p[jj] = (bh)tile[rr + jj][oc];
    *(bh8*)(O + (size_t)(c0 + oc) * R + r0 + rr) = p;
  }
}

extern "C" void kernel_launch(void* const* d_in, const int* in_sizes, int n_in,
                              void* d_out, int out_size, void* d_ws, size_t ws_size,
                              hipStream_t stream) {
  (void)in_sizes; (void)n_in; (void)out_size; (void)ws_size;
  const int* x = (const int*)d_in[0];
  const float* emb = (const float*)d_in[2];
  const float* Wq = (const float*)d_in[3];
  const float* bq = (const float*)d_in[4];
  const float* Wk = (const float*)d_in[5];
  const float* bk = (const float*)d_in[6];
  const float* Wv = (const float*)d_in[7];
  const float* bv = (const float*)d_in[8];
  const float* Wo = (const float*)d_in[9];
  const float* bo = (const float*)d_in[10];
  const float* g1 = (const float*)d_in[11];
  const float* be1 = (const float*)d_in[12];
  const float* g2 = (const float*)d_in[13];
  const float* be2 = (const float*)d_in[14];
  const float* W1 = (const float*)d_in[15];
  const float* b1 = (const float*)d_in[16];
  const float* W2 = (const float*)d_in[17];
  const float* b2 = (const float*)d_in[18];
  const float* Wout = (const float*)d_in[19];
  const float* bout = (const float*)d_in[20];
  float* logits = (float*)d_out;
  char* ws = (char*)d_ws;
  // workspace layout (bytes); total ~271 MB
  float* h  = (float*)(ws + 0);          // [2048,1024] f32 residual stream
  float* tb = (float*)(ws + 8388608);    // [2048,1024] f32 pre-LN
  bh* hb    = (bh*)(ws + 16777216);      // [2048,1024] bf16
  bh* qb    = (bh*)(ws + 20971520);      // [2048,1024]
  bh* kb    = (bh*)(ws + 25165824);      // [2048,1024]
  bh* vT    = (bh*)(ws + 29360128);      // [B,H,64,S]
  bh* ctx   = (bh*)(ws + 33554432);      // [2048,1024]
  bh* ff    = (bh*)(ws + 37748736);      // [2048,4096]
  bh* wqkvT = (bh*)(ws + 54525952);      // [3][6][1024][1024]
  bh* woT   = (bh*)(ws + 92274688);      // [6][1024][1024]
  bh* w1T   = (bh*)(ws + 104857600);     // [6][4096][1024]
  bh* w2T   = (bh*)(ws + 155189248);     // [6][1024][4096]
  bh* woutT = (bh*)(ws + 205520896);     // [32000][1024]

  dim3 B256(256);
  k_transpose<<<dim3(16, 16, 6), B256, 0, stream>>>(Wq, wqkvT, 1024, 1024);
  k_transpose<<<dim3(16, 16, 6), B256, 0, stream>>>(Wk, wqkvT + (size_t)6 * 1048576, 1024, 1024);
  k_transpose<<<dim3(16, 16, 6), B256, 0, stream>>>(Wv, wqkvT + (size_t)12 * 1048576, 1024, 1024);
  k_transpose<<<dim3(16, 16, 6), B256, 0, stream>>>(Wo, woT, 1024, 1024);
  k_transpose<<<dim3(64, 16, 6), B256, 0, stream>>>(W1, w1T, 1024, 4096);
  k_transpose<<<dim3(16, 64, 6), B256, 0, stream>>>(W2, w2T, 4096, 1024);
  k_transpose<<<dim3(500, 16, 1), B256, 0, stream>>>(Wout, woutT, 1024, 32000);
  k_embed<<<dim3(2048), B256, 0, stream>>>(x, emb, h, hb);
  for (int l = 0; l < 6; l++) {
    k_gemm_qkv<<<dim3(8, 16, 3), B256, 0, stream>>>(hb, wqkvT + (size_t)l * 1048576,
        bq + l * 1024, bk + l * 1024, bv + l * 1024, qb, kb, vT);
    k_attn<<<dim3(16, 32), B256, 0, stream>>>(qb, kb, vT, ctx);
    k_gemm_epi<3><<<dim3(8, 16), B256, 0, stream>>>(ctx, woT + (size_t)l * 1048576,
        bo + l * 1024, h, tb, 1024, 1024);
    k_ln<<<dim3(2048), B256, 0, stream>>>(tb, g1 + l * 1024, be1 + l * 1024, h, hb);
    k_gemm_epi<2><<<dim3(32, 16), B256, 0, stream>>>(hb, w1T + (size_t)l * 4194304,
        b1 + l * 4096, nullptr, ff, 4096, 1024);
    k_gemm_epi<3><<<dim3(8, 16), B256, 0, stream>>>(ff, w2T + (size_t)l * 4194304,
        b2 + l * 1024, h, tb, 1024, 4096);
    k_ln<<<dim3(2048), B256, 0, stream>>>(tb, g2 + l * 1024, be2 + l * 1024, h, hb);
  }
  k_gemm_epi<4><<<dim3(250, 16), B256, 0, stream>>>(hb, woutT, bout, nullptr, logits, 32000, 1024);
}